// Round 13
// baseline (150.133 us; speedup 1.0000x reference)
//
#include <hip/hip_runtime.h>
#include <stdint.h>

typedef __attribute__((ext_vector_type(8))) short short8;
typedef __attribute__((ext_vector_type(4))) float f32x4;
typedef __attribute__((ext_vector_type(16))) float f32x16;

#define MFMA16(a, b, c) __builtin_amdgcn_mfma_f32_16x16x32_bf16((a), (b), (c), 0, 0, 0)
#define MFMA32(a, b, c) __builtin_amdgcn_mfma_f32_32x32x16_bf16((a), (b), (c), 0, 0, 0)

__device__ inline unsigned short f2bf(float x) {
  unsigned u = __float_as_uint(x);
  u = (u + 0x7FFFu + ((u >> 16) & 1u)) >> 16;
  return (unsigned short)u;
}

// async global->LDS, 16B per lane. LDS dest is wave-uniform base + lane*16.
__device__ inline void gload16(const unsigned short* g, unsigned short* l) {
  __builtin_amdgcn_global_load_lds(
      (const __attribute__((address_space(1))) unsigned int*)g,
      (__attribute__((address_space(3))) unsigned int*)l, 16, 0, 0);
}

__device__ inline short8 lds8(const unsigned short* base, int byteoff) {
  return *reinterpret_cast<const short8*>(reinterpret_cast<const char*>(base) + byteoff);
}

// pack two f32 -> one dword of 2 bf16 (RNE)
__device__ inline unsigned cvtpk(float lo, float hi) {
  unsigned r;
  asm("v_cvt_pk_bf16_f32 %0, %1, %2" : "=v"(r) : "v"(lo), "v"(hi));
  return r;
}
// swap vdst.hi32lanes <-> vsrc.lo32lanes
__device__ inline void plswap(unsigned& a, unsigned& b) {
  asm volatile("v_permlane32_swap_b32 %0, %1" : "+v"(a), "+v"(b));
}
__device__ inline float swapadd(float v) {
  float a = v, b;
  asm volatile("v_mov_b32 %1, %0\n\tv_permlane32_swap_b32 %0, %1" : "+v"(a), "=&v"(b));
  return a + b;
}

__device__ inline short8 mk8(unsigned a, unsigned b, unsigned c, unsigned d) {
  union { unsigned u[4]; short8 v; } x;
  x.u[0] = a; x.u[1] = b; x.u[2] = c; x.u[3] = d;
  return x.v;
}

// byte offset into a [rows][64] bf16 linear LDS tile, XOR-swizzled.
__device__ inline int swz(int row, int chunk) {
  return row * 128 + (((chunk) ^ (row & 7)) << 4);
}

// exp2 of 16 scores -> row-sum partial (in-lane tree) + two bf16 A-frags
__device__ inline void exppack(const f32x16& sv, float& lsum, short8& paLo, short8& paHi) {
  float p[16];
#pragma unroll
  for (int i = 0; i < 16; ++i) p[i] = __builtin_amdgcn_exp2f(sv[i]);
  float q8[8];
#pragma unroll
  for (int i = 0; i < 8; ++i) q8[i] = p[2 * i] + p[2 * i + 1];
#pragma unroll
  for (int s2 = 4; s2 > 0; s2 >>= 1)
#pragma unroll
    for (int i = 0; i < s2; ++i) q8[i] += q8[i + s2];
  lsum += q8[0];
  unsigned w0 = cvtpk(p[0], p[1]), w1 = cvtpk(p[2], p[3]);
  unsigned w2 = cvtpk(p[4], p[5]), w3 = cvtpk(p[6], p[7]);
  plswap(w0, w2); plswap(w1, w3);
  unsigned w4 = cvtpk(p[8], p[9]), w5 = cvtpk(p[10], p[11]);
  unsigned w6 = cvtpk(p[12], p[13]), w7 = cvtpk(p[14], p[15]);
  plswap(w4, w6); plswap(w5, w7);
  paLo = mk8(w0, w1, w2, w3);
  paHi = mk8(w4, w5, w6, w7);
}

// ---------------- fp32 -> bf16 conversion, 4 arrays in one launch ----------------
__global__ __launch_bounds__(256) void cvt_bf16x(const float* __restrict__ a0,
                                                 const float* __restrict__ a1,
                                                 const float* __restrict__ a2,
                                                 const float* __restrict__ a3,
                                                 unsigned short* __restrict__ d, int per) {
  int y = blockIdx.y;
  const float* s = (y == 0) ? a0 : (y == 1) ? a1 : (y == 2) ? a2 : a3;
  int i = (blockIdx.x * 256 + threadIdx.x) * 8;
  if (i >= per) return;
  float4 v0 = *reinterpret_cast<const float4*>(s + i);
  float4 v1 = *reinterpret_cast<const float4*>(s + i + 4);
  short8 o;
  o[0] = (short)f2bf(v0.x); o[1] = (short)f2bf(v0.y);
  o[2] = (short)f2bf(v0.z); o[3] = (short)f2bf(v0.w);
  o[4] = (short)f2bf(v1.x); o[5] = (short)f2bf(v1.y);
  o[6] = (short)f2bf(v1.z); o[7] = (short)f2bf(v1.w);
  *reinterpret_cast<short8*>(d + (size_t)y * per + i) = o;
}

// ---------------- Projection GEMM: 32x32 MFMA, 128x128 tile, counted vmcnt -------
// A: [4096][1024] bf16 (q/k/v by z), W: [1024][1024] bf16 row-major.
// Grid 768 (XCD-swizzled, by-fastest). 4 waves, each owns 64(m)x64(e) via 2x2
// MFMA32 tiles -> 2x FLOP per LDS byte vs 16x16. D layout: m in regs, e in lanes.
// K-loop: STAGE(t+1) -> vmcnt(8) -> barrier -> COMPUTE(t) -> barrier.
// z=0: Q scaled by log2(e)/8, [B*H][S][64]; z=1: K same; z=2: V^T [B*H][64][S].
__global__ __launch_bounds__(256) void gemm_proj(
    const unsigned short* __restrict__ Abase, const unsigned short* __restrict__ Wbase,
    const float* __restrict__ bias0, const float* __restrict__ bias1,
    const float* __restrict__ bias2, unsigned short* __restrict__ Obase) {
  const int M = 4096, N = 1024, K = 1024;
  const int orig = blockIdx.x;
  const int wg = (orig & 7) * 96 + (orig >> 3);
  const int z = wg >> 8;
  const int rr_ = wg & 255;
  const int by = rr_ & 7, bx = rr_ >> 3;

  const unsigned short* A = Abase + (size_t)z * M * K;
  const unsigned short* W = Wbase + (size_t)z * N * K;
  const float* bias = (z == 0) ? bias0 : (z == 1 ? bias1 : bias2);

  __shared__ unsigned short As[2 * 128 * 64];  // 32 KB
  __shared__ unsigned short Bs[2 * 128 * 64];  // 32 KB

  const int t = threadIdx.x, lane = t & 63, w = t >> 6;
  const int wm = w >> 1, wn = w & 1;
  const int m0 = bx * 128, n0 = by * 128;
  const int l31 = lane & 31, hi = lane >> 5;

  f32x16 acc[2][2] = {};  // [mb][eb]

  // staging geometry (pre-inverse-swizzled source)
  int srow[4], scol[4];
#pragma unroll
  for (int p = 0; p < 4; ++p) {
    int c = (p * 4 + w) * 64 + lane;
    srow[p] = c >> 3; scol[p] = ((c & 7) ^ (srow[p] & 7)) * 8;
  }
  // fragment read offsets within one 16KB buffer
  int afoff[2][4], wfoff[2][4];
#pragma unroll
  for (int mb = 0; mb < 2; ++mb) {
    int rowA = wm * 64 + mb * 32 + l31;
    int rowW = wn * 64 + mb * 32 + l31;
#pragma unroll
    for (int kc = 0; kc < 4; ++kc) {
      afoff[mb][kc] = rowA * 128 + (((kc * 2 + hi) ^ (rowA & 7)) << 4);
      wfoff[mb][kc] = rowW * 128 + (((kc * 2 + hi) ^ (rowW & 7)) << 4);
    }
  }

#define STAGE_P(kt, buf)                                                              \
  {                                                                                   \
    _Pragma("unroll") for (int p = 0; p < 4; ++p)                                     \
        gload16(&A[(size_t)(m0 + srow[p]) * K + (kt) + scol[p]],                      \
                &As[(buf)*8192 + ((p * 4 + w) * 64) * 8]);                            \
    _Pragma("unroll") for (int p = 0; p < 4; ++p)                                     \
        gload16(&W[(size_t)(n0 + srow[p]) * K + (kt) + scol[p]],                      \
                &Bs[(buf)*8192 + ((p * 4 + w) * 64) * 8]);                            \
  }

#define COMPUTE_P(buf)                                                                \
  {                                                                                   \
    _Pragma("unroll") for (int kc = 0; kc < 4; ++kc) {                                \
      short8 af0 = lds8(As, (buf)*16384 + afoff[0][kc]);                              \
      short8 af1 = lds8(As, (buf)*16384 + afoff[1][kc]);                              \
      short8 wf0 = lds8(Bs, (buf)*16384 + wfoff[0][kc]);                              \
      short8 wf1 = lds8(Bs, (buf)*16384 + wfoff[1][kc]);                              \
      acc[0][0] = MFMA32(af0, wf0, acc[0][0]);                                        \
      acc[0][1] = MFMA32(af0, wf1, acc[0][1]);                                        \
      acc[1][0] = MFMA32(af1, wf0, acc[1][0]);                                        \
      acc[1][1] = MFMA32(af1, wf1, acc[1][1]);                                        \
    }                                                                                 \
  }

  // prologue: issue step-0 loads (8 in flight)
  STAGE_P(0, 0);

  int cur = 0;
  for (int kt = 0; kt < K; kt += 64) {
    int ktn = (kt + 64 < K) ? kt + 64 : 0;
    STAGE_P(ktn, cur ^ 1);
    // step t's 8 loads complete; t+1's 8 remain in flight across compute
    asm volatile("s_waitcnt vmcnt(8)" ::: "memory");
    __builtin_amdgcn_sched_barrier(0);
    __builtin_amdgcn_s_barrier();
    __builtin_amdgcn_sched_barrier(0);
    COMPUTE_P(cur);
    __builtin_amdgcn_sched_barrier(0);
    __builtin_amdgcn_s_barrier();
    __builtin_amdgcn_sched_barrier(0);
    cur ^= 1;
  }
#undef STAGE_P
#undef COMPUTE_P

  // epilogue. D: m = m0+wm*64+mb*32+(r&3)+8*(r>>2)+4*hi ; e = n0+wn*64+eb*32+l31
  const float scale = (z == 0) ? 0.18033688011112042f : 1.0f;
  if (z < 2) {
    unsigned short* O = Obase + (size_t)z * M * N;
#pragma unroll
    for (int eb = 0; eb < 2; ++eb) {
      int e = n0 + wn * 64 + eb * 32 + l31;
      float be = bias[e];
      int h = e >> 6, d = e & 63;
#pragma unroll
      for (int mb = 0; mb < 2; ++mb)
#pragma unroll
        for (int r = 0; r < 16; ++r) {
          int m = m0 + wm * 64 + mb * 32 + (r & 3) + 8 * (r >> 2) + 4 * hi;
          int s = m >> 1, bb = m & 1;
          O[(((size_t)(bb * 16 + h) * 2048 + s) << 6) + d] = f2bf((acc[mb][eb][r] + be) * scale);
        }
    }
  } else {
    unsigned short* O = Obase + (size_t)2 * M * N;  // Vt[bh][d][s]
#pragma unroll
    for (int eb = 0; eb < 2; ++eb) {
      int e = n0 + wn * 64 + eb * 32 + l31;
      float be = bias[e];
      int h = e >> 6, d = e & 63;
#pragma unroll
      for (int mb = 0; mb < 2; ++mb)
#pragma unroll
        for (int r = 0; r < 16; ++r) {
          int m = m0 + wm * 64 + mb * 32 + (r & 3) + 8 * (r >> 2) + 4 * hi;
          int s = m >> 1, bb = m & 1;
          O[(((size_t)(bb * 16 + h) * 64 + d) << 11) + s] = f2bf(acc[mb][eb][r] + be);
        }
    }
  }
}

// ---------------- Output GEMM (R12 MODE1): counted-vmcnt, BN=64, 16x16 -----------
__global__ __launch_bounds__(256) void gemm_out(
    const unsigned short* __restrict__ A, const unsigned short* __restrict__ W,
    const float* __restrict__ bias, float* __restrict__ O, int M, int N, int K) {
  const int orig = blockIdx.x;
  const int wg = (orig & 7) * 64 + (orig >> 3);
  const int by = wg & 15, bx = wg >> 4;

  __shared__ unsigned short As[2 * 128 * 64];  // 32 KB
  __shared__ unsigned short Bs[2 * 64 * 64];   // 16 KB

  const int t = threadIdx.x, lane = t & 63, w = t >> 6;
  const int wm = w >> 1, wn = w & 1;
  const int m0 = bx * 128, n0 = by * 64;
  const int lrow = lane & 15, lg = lane >> 4;

  f32x4 acc[4][2] = {};

  int arow[4], acol[4], brow[2], bcol[2];
#pragma unroll
  for (int p = 0; p < 4; ++p) {
    int c = (p * 4 + w) * 64 + lane;
    arow[p] = c >> 3; acol[p] = ((c & 7) ^ (arow[p] & 7)) * 8;
  }
#pragma unroll
  for (int p = 0; p < 2; ++p) {
    int c = (p * 4 + w) * 64 + lane;
    brow[p] = c >> 3; bcol[p] = ((c & 7) ^ (brow[p] & 7)) * 8;
  }

#define STAGE_G(kt, buf)                                                              \
  {                                                                                   \
    _Pragma("unroll") for (int p = 0; p < 4; ++p)                                     \
        gload16(&A[(size_t)(m0 + arow[p]) * K + (kt) + acol[p]],                      \
                &As[(buf)*8192 + ((p * 4 + w) * 64) * 8]);                            \
    _Pragma("unroll") for (int p = 0; p < 2; ++p)                                     \
        gload16(&W[(size_t)(n0 + brow[p]) * K + (kt) + bcol[p]],                      \
                &Bs[(buf)*4096 + ((p * 4 + w) * 64) * 8]);                            \
  }

#define COMPUTE(buf)                                                                  \
  {                                                                                   \
    _Pragma("unroll") for (int kc = 0; kc < 2; ++kc) {                                \
      short8 af[4], bfr[2];                                                           \
      _Pragma("unroll") for (int i = 0; i < 4; ++i)                                   \
          af[i] = lds8(As, (buf)*16384 + swz(wm * 64 + i * 16 + lrow, kc * 4 + lg));  \
      _Pragma("unroll") for (int i = 0; i < 2; ++i)                                   \
          bfr[i] = lds8(Bs, (buf)*8192 + swz(wn * 32 + i * 16 + lrow, kc * 4 + lg));  \
      _Pragma("unroll") for (int mi = 0; mi < 4; ++mi)                                \
          _Pragma("unroll") for (int ni = 0; ni < 2; ++ni)                            \
              acc[mi][ni] = MFMA16(af[mi], bfr[ni], acc[mi][ni]);                     \
    }                                                                                 \
  }

  STAGE_G(0, 0);
  int cur = 0;
  for (int kt = 0; kt < K; kt += 64) {
    int ktn = (kt + 64 < K) ? kt + 64 : 0;
    STAGE_G(ktn, cur ^ 1);
    asm volatile("s_waitcnt vmcnt(6)" ::: "memory");
    __builtin_amdgcn_sched_barrier(0);
    __builtin_amdgcn_s_barrier();
    __builtin_amdgcn_sched_barrier(0);
    COMPUTE(cur);
    __builtin_amdgcn_sched_barrier(0);
    __builtin_amdgcn_s_barrier();
    __builtin_amdgcn_sched_barrier(0);
    cur ^= 1;
  }
#undef STAGE_G
#undef COMPUTE

  const int r0 = lg * 4;
#pragma unroll
  for (int mi = 0; mi < 4; ++mi)
#pragma unroll
    for (int ni = 0; ni < 2; ++ni) {
      int e = n0 + wn * 32 + ni * 16 + lrow;
      float be = bias[e];
#pragma unroll
      for (int r = 0; r < 4; ++r) {
        int m = m0 + wm * 64 + mi * 16 + r0 + r;
        O[(size_t)m * N + e] = acc[mi][ni][r] + be;
      }
    }
}

// ---------------- Flash attention, 32x32 MFMA, swapped QK^T, 2-tile pipeline ----
// (round-8 version: ring-4, vmcnt(4), QK(t+1) overlaps exp/pack(t), grid 512)
__global__ __launch_bounds__(256, 2) void attn(const unsigned short* __restrict__ Q,
                                               const unsigned short* __restrict__ K,
                                               const unsigned short* __restrict__ Vt,
                                               unsigned short* __restrict__ ctx) {
  __shared__ unsigned short Ks[4 * 4096];  // ring of 4: [buf][64 key][64 dk]
  __shared__ unsigned short Vs[4 * 4096];  // ring of 4: [buf][64 d][64 key]

  // XCD swizzle: nwg=512, chunk=64 -> XCD x owns bh range [x*4, x*4+4)
  const int orig = blockIdx.x;
  const int wg = ((orig & 7) << 6) + (orig >> 3);
  const int bh = wg >> 4;
  const int qb = wg & 15;

  const int t = threadIdx.x, lane = t & 63, wv = t >> 6;
  const int q0 = qb * 128 + wv * 32;
  const int q = lane & 31, hi = lane >> 5;
  const int fq = (q ^ (q >> 3)) & 7;

  const unsigned short* Qb = Q + ((size_t)bh * 2048 + q0) * 64;
  const unsigned short* Kb = K + (size_t)bh * 2048 * 64;
  const unsigned short* Vb = Vt + (size_t)bh * 64 * 2048;

  short8 qf[4];
#pragma unroll
  for (int m = 0; m < 4; ++m)
    qf[m] = *reinterpret_cast<const short8*>(&Qb[q * 64 + m * 16 + hi * 8]);

  // loop-invariant LDS byte offsets (within one 8KB buffer)
  int koff[2][4], voff[2][2][2];
#pragma unroll
  for (int st = 0; st < 2; ++st) {
    int f = fq ^ (st ? 4 : 0);
#pragma unroll
    for (int m = 0; m < 4; ++m)
      koff[st][m] = (st * 32 + q) * 128 + (((m * 2 + hi) ^ f) << 4);
  }
#pragma unroll
  for (int dh = 0; dh < 2; ++dh) {
    int f = fq ^ (dh ? 4 : 0);
#pragma unroll
    for (int st = 0; st < 2; ++st)
#pragma unroll
      for (int kc = 0; kc < 2; ++kc)
        voff[dh][st][kc] = (dh * 32 + q) * 128 + (((st * 4 + kc * 2 + hi) ^ f) << 4);
  }

  // staging source addresses (pre-inverse-swizzled), advance per tile
  int c0 = wv * 64 + lane, c1 = (4 + wv) * 64 + lane;
  int sr0 = c0 >> 3, sr1 = c1 >> 3;
  int sc0c = ((c0 & 7) ^ ((sr0 ^ (sr0 >> 3)) & 7)) * 8;
  int sc1c = ((c1 & 7) ^ ((sr1 ^ (sr1 >> 3)) & 7)) * 8;
  const unsigned short* ks0 = Kb + (size_t)sr0 * 64 + sc0c;
  const unsigned short* ks1 = Kb + (size_t)sr1 * 64 + sc1c;
  const unsigned short* vp0 = Vb + (size_t)sr0 * 2048 + sc0c;
  const unsigned short* vp1 = Vb + (size_t)sr1 * 2048 + sc1c;

#define STAGE(tt)                                                      \
  {                                                                    \
    char* kb = (char*)Ks + ((tt) & 3) * 8192;                          \
    char* vb2 = (char*)Vs + ((tt) & 3) * 8192;                         \
    gload16(ks0, (unsigned short*)(kb + wv * 1024));                   \
    gload16(ks1, (unsigned short*)(kb + (4 + wv) * 1024));             \
    gload16(vp0, (unsigned short*)(vb2 + wv * 1024));                  \
    gload16(vp1, (unsigned short*)(vb2 + (4 + wv) * 1024));            \
    ks0 += 4096; ks1 += 4096; vp0 += 64; vp1 += 64;                    \
  }

  f32x16 oa0 = {}, oa1 = {};
  float lsum = 0.f;
  const f32x16 zero16 = {};
  f32x16 sA0 = {}, sA1 = {}, sB0, sB1;

  // prologue: stage tiles 0,1,2; rendezvous with tile0 resident; QK(0) -> sA
  STAGE(0); STAGE(1); STAGE(2);
  asm volatile("s_waitcnt vmcnt(8)" ::: "memory");
  __builtin_amdgcn_s_barrier();
  __builtin_amdgcn_sched_barrier(0);
#pragma unroll
  for (int m = 0; m < 4; ++m) {
    sA0 = MFMA32(lds8(Ks, koff[0][m]), qf[m], sA0);
    sA1 = MFMA32(lds8(Ks, koff[1][m]), qf[m], sA1);
  }

  // PHASE(tcur): wait tile tcur+1 resident; stage tcur+3; QK(tcur+1)->sN;
  //              exp/pack(sC) [overlaps QK on VALU pipe]; PV(tcur, pa).
#define PHASE(tcur, sC0, sC1, sN0, sN1)                                         \
  {                                                                             \
    asm volatile("s_waitcnt vmcnt(4)" ::: "memory");                            \
    __builtin_amdgcn_sched_barrier(0);                                          \
    __builtin_amdgcn_s_barrier();                                               \
    __builtin_amdgcn_sched_barrier(0);                                          \
    STAGE((tcur) + 3);                                                          \
    sN0 = zero16; sN1 = zero16;                                                 \
    __builtin_amdgcn_s_setprio(1);                                              \
    {                                                                           \
      const int so = (((tcur) + 1) & 3) * 8192;                                 \
      _Pragma("unroll") for (int m = 0; m < 4; ++m) {                           \
        sN0 = MFMA32(lds8(Ks, so + koff[0][m]), qf[m], sN0);                    \
        sN1 = MFMA32(lds8(Ks, so + koff[1][m]), qf[m], sN1);                    \
      }                                                                         \
    }                                                                           \
    short8 paL0, paH0, paL1, paH1;                                              \
    exppack(sC0, lsum, paL0, paH0);                                             \
    exppack(sC1, lsum, paL1, paH1);                                             \
    {                                                                           \
      const int vo = ((tcur) & 3) * 8192;                                       \
      oa0 = MFMA32(paL0, lds8(Vs, vo + voff[0][0][0]), oa0);                    \
      oa1 = MFMA32(paL0, lds8(Vs, vo + voff[1][0][0]), oa1);                    \
      oa0 = MFMA32(paH0, lds8(Vs, vo + voff[0][0][1]), oa0);                    \
      oa1 = MFMA32(paH0, lds8(Vs, vo + voff[1][0][1]), oa1);                    \
      oa0 = MFMA32(paL1, lds8(Vs, vo + voff[0][1][0]), oa0);                    \
      oa1 = MFMA32(paL1, lds8(Vs, vo + voff[1][1][0]), oa1);                    \
      oa0 = MFMA32(paH1, lds8(Vs, vo + voff[0][1][1]), oa0);                    \
      oa1 = MFMA32(paH1, lds8(Vs, vo + voff[1][1][1]), oa1);                    \
    }                                                                           \
    __builtin_amdgcn_s_setprio(0);                                              \
  }

  for (int it = 0; it < 15; ++it) {
    int tc = 2 * it;
    PHASE(tc, sA0, sA1, sB0, sB1);
    PHASE(tc + 1, sB0, sB1, sA0, sA1);
  }
  PHASE(30, sA0, sA1, sB0, sB1);  // QK(31)->sB, PV(30)

  // tail: tile 31 (slot 3) from sB; V(31) resident since PHASE(30)'s wait+barrier
  {
    short8 paL0, paH0, paL1, paH1;
    exppack(sB0, lsum, paL0, paH0);
    exppack(sB1, lsum, paL1, paH1);
    const int vo = 3 * 8192;
    oa0 = MFMA32(paL0, lds8(Vs, vo + voff[0][0][0]), oa0);
    oa1 = MFMA32(paL0, lds8(Vs, vo + voff[1][0][0]), oa1);
    oa0 = MFMA32(paH0, lds8(Vs, vo + voff[0][0][1]), oa0);
    oa1 = MFMA32(paH0, lds8(Vs, vo + voff[1][0][1]), oa1);
    oa0 = MFMA32(paL1, lds8(Vs, vo + voff[0][1][0]), oa0);
    oa1 = MFMA32(paL1, lds8(Vs, vo + voff[1][1][0]), oa1);
    oa0 = MFMA32(paH1, lds8(Vs, vo + voff[0][1][1]), oa0);
    oa1 = MFMA32(paH1, lds8(Vs, vo + voff[1][1][1]), oa1);
  }
#undef PHASE
#undef STAGE

  // epilogue: combine hi/lo key-half sums, normalize, store
  lsum = swapadd(lsum);
  float linv = 1.0f / lsum;
  const int b = bh >> 4, h = bh & 15;
#pragma unroll
  for (int r = 0; r < 16; ++r) {
    int qr = (r & 3) + 8 * (r >> 2) + 4 * hi;
    float li = __shfl(linv, qr);
    size_t base = ((size_t)(q0 + qr) * 2 + b) * 1024 + h * 64 + q;
    ctx[base] = f2bf(oa0[r] * li);
    ctx[base + 32] = f2bf(oa1[r] * li);
  }
}

// ---------------- host ----------------
extern "C" void kernel_launch(void* const* d_in, const int* in_sizes, int n_in, void* d_out,
                              int out_size, void* d_ws, size_t ws_size, hipStream_t stream) {
  const float* q  = (const float*)d_in[0];
  const float* k  = (const float*)d_in[1];
  const float* v  = (const float*)d_in[2];
  const float* Wq = (const float*)d_in[3];
  const float* bq = (const float*)d_in[4];
  const float* Wk = (const float*)d_in[5];
  const float* bk = (const float*)d_in[6];
  const float* Wv = (const float*)d_in[7];
  const float* bv = (const float*)d_in[8];
  const float* Wo = (const float*)d_in[9];
  const float* bo = (const float*)d_in[10];

  const size_t SZ_IN = 4194304;  // 4096*1024
  const size_t SZ_W  = 1048576;  // 1024*1024
  unsigned short* ws  = (unsigned short*)d_ws;
  unsigned short* xb  = ws;                 // q,k,v bf16       (3*SZ_IN)
  unsigned short* Wb  = xb + 3 * SZ_IN;     // Wq,Wk,Wv,Wo bf16 (4*SZ_W)
  unsigned short* QKV = Wb + 4 * SZ_W;      // Q,K (by-head), Vt (transposed)
  unsigned short* ctx = QKV + 3 * SZ_IN;    // context          (SZ_IN)

  cvt_bf16x<<<dim3(SZ_IN / 2048, 3), 256, 0, stream>>>(q, k, v, v, xb, (int)SZ_IN);
  cvt_bf16x<<<dim3(SZ_W / 2048, 4), 256, 0, stream>>>(Wq, Wk, Wv, Wo, Wb, (int)SZ_W);

  gemm_proj<<<768, 256, 0, stream>>>(xb, Wb, bq, bk, bv, QKV);
  attn<<<512, 256, 0, stream>>>(QKV, QKV + SZ_IN, QKV + 2 * SZ_IN, ctx);
  gemm_out<<<512, 256, 0, stream>>>(ctx, Wb + 3 * SZ_W, bo, (float*)d_out, 4096, 1024, 1024);
}

// Round 14
// 118.255 us; speedup vs baseline: 1.2696x; 1.2696x over previous
//
#include <hip/hip_runtime.h>
#include <stdint.h>

typedef __attribute__((ext_vector_type(8))) short short8;
typedef __attribute__((ext_vector_type(4))) float f32x4;
typedef __attribute__((ext_vector_type(16))) float f32x16;

#define MFMA16(a, b, c) __builtin_amdgcn_mfma_f32_16x16x32_bf16((a), (b), (c), 0, 0, 0)
#define MFMA32(a, b, c) __builtin_amdgcn_mfma_f32_32x32x16_bf16((a), (b), (c), 0, 0, 0)

__device__ inline unsigned short f2bf(float x) {
  unsigned u = __float_as_uint(x);
  u = (u + 0x7FFFu + ((u >> 16) & 1u)) >> 16;
  return (unsigned short)u;
}

// async global->LDS, 16B per lane. LDS dest is wave-uniform base + lane*16.
__device__ inline void gload16(const unsigned short* g, unsigned short* l) {
  __builtin_amdgcn_global_load_lds(
      (const __attribute__((address_space(1))) unsigned int*)g,
      (__attribute__((address_space(3))) unsigned int*)l, 16, 0, 0);
}

__device__ inline short8 lds8(const unsigned short* base, int byteoff) {
  return *reinterpret_cast<const short8*>(reinterpret_cast<const char*>(base) + byteoff);
}

// pack two f32 -> one dword of 2 bf16 (RNE)
__device__ inline unsigned cvtpk(float lo, float hi) {
  unsigned r;
  asm("v_cvt_pk_bf16_f32 %0, %1, %2" : "=v"(r) : "v"(lo), "v"(hi));
  return r;
}
// swap vdst.hi32lanes <-> vsrc.lo32lanes
__device__ inline void plswap(unsigned& a, unsigned& b) {
  asm volatile("v_permlane32_swap_b32 %0, %1" : "+v"(a), "+v"(b));
}
__device__ inline float swapadd(float v) {
  float a = v, b;
  asm volatile("v_mov_b32 %1, %0\n\tv_permlane32_swap_b32 %0, %1" : "+v"(a), "=&v"(b));
  return a + b;
}

__device__ inline short8 mk8(unsigned a, unsigned b, unsigned c, unsigned d) {
  union { unsigned u[4]; short8 v; } x;
  x.u[0] = a; x.u[1] = b; x.u[2] = c; x.u[3] = d;
  return x.v;
}

// byte offset into a [rows][64] bf16 linear LDS tile, XOR-swizzled.
__device__ inline int swz(int row, int chunk) {
  return row * 128 + (((chunk) ^ (row & 7)) << 4);
}

// exp2 of 16 scores -> row-sum partial (in-lane tree) + two bf16 A-frags
__device__ inline void exppack(const f32x16& sv, float& lsum, short8& paLo, short8& paHi) {
  float p[16];
#pragma unroll
  for (int i = 0; i < 16; ++i) p[i] = __builtin_amdgcn_exp2f(sv[i]);
  float q8[8];
#pragma unroll
  for (int i = 0; i < 8; ++i) q8[i] = p[2 * i] + p[2 * i + 1];
#pragma unroll
  for (int s2 = 4; s2 > 0; s2 >>= 1)
#pragma unroll
    for (int i = 0; i < s2; ++i) q8[i] += q8[i + s2];
  lsum += q8[0];
  unsigned w0 = cvtpk(p[0], p[1]), w1 = cvtpk(p[2], p[3]);
  unsigned w2 = cvtpk(p[4], p[5]), w3 = cvtpk(p[6], p[7]);
  plswap(w0, w2); plswap(w1, w3);
  unsigned w4 = cvtpk(p[8], p[9]), w5 = cvtpk(p[10], p[11]);
  unsigned w6 = cvtpk(p[12], p[13]), w7 = cvtpk(p[14], p[15]);
  plswap(w4, w6); plswap(w5, w7);
  paLo = mk8(w0, w1, w2, w3);
  paHi = mk8(w4, w5, w6, w7);
}

// ---------------- fp32 -> bf16 conversion, 4 arrays in one launch ----------------
__global__ __launch_bounds__(256) void cvt_bf16x(const float* __restrict__ a0,
                                                 const float* __restrict__ a1,
                                                 const float* __restrict__ a2,
                                                 const float* __restrict__ a3,
                                                 unsigned short* __restrict__ d, int per) {
  int y = blockIdx.y;
  const float* s = (y == 0) ? a0 : (y == 1) ? a1 : (y == 2) ? a2 : a3;
  int i = (blockIdx.x * 256 + threadIdx.x) * 8;
  if (i >= per) return;
  float4 v0 = *reinterpret_cast<const float4*>(s + i);
  float4 v1 = *reinterpret_cast<const float4*>(s + i + 4);
  short8 o;
  o[0] = (short)f2bf(v0.x); o[1] = (short)f2bf(v0.y);
  o[2] = (short)f2bf(v0.z); o[3] = (short)f2bf(v0.w);
  o[4] = (short)f2bf(v1.x); o[5] = (short)f2bf(v1.y);
  o[6] = (short)f2bf(v1.z); o[7] = (short)f2bf(v1.w);
  *reinterpret_cast<short8*>(d + (size_t)y * per + i) = o;
}

// ---------------- GEMM: C = A @ W^T + bias, 2-phase pipelined, BN=64 ----------------
// A: [M][K] bf16 row-major, W: [N][K] bf16 row-major. 1-D grid, XCD-swizzled.
// MODE 0 (grid 1536): z=0 -> Q scaled by log2(e)/8, [B*H][S][64]; z=1 -> K same;
//                     z=2 -> V transposed [B*H][64][S] (LDS-staged coalesced writes).
// MODE 1 (grid 512): fp32 out row-major [M][N] (final projection).
// K-loop: STAGE(t+1) -> compute(t) -> vmcnt(0)+barrier; last step peeled.
// LDS = 48 KB -> 3 blocks/CU co-resident.
template <int MODE>
__global__ __launch_bounds__(256) void gemm_bt(
    const unsigned short* __restrict__ Abase, const unsigned short* __restrict__ Wbase,
    const float* __restrict__ bias0, const float* __restrict__ bias1,
    const float* __restrict__ bias2, unsigned short* __restrict__ ObaseBf,
    float* __restrict__ ObaseF, int M, int N, int K) {
  constexpr int CHUNK = (MODE == 0) ? 192 : 64;  // nwg/8 for XCD swizzle

  const int orig = blockIdx.x;
  const int wg = (orig & 7) * CHUNK + (orig >> 3);
  int z, bx, by;
  if (MODE == 0) {
    z = wg >> 9;
    int r = wg & 511;
    by = r & 15;   // by-fastest: 16 W-panels cycle within the XCD chunk
    bx = r >> 4;
  } else {
    z = 0; by = wg & 15; bx = wg >> 4;
  }

  const unsigned short* A = Abase + (size_t)z * M * K;
  const unsigned short* W = Wbase + (size_t)z * N * K;
  const float* bias = (z == 0) ? bias0 : (z == 1 ? bias1 : bias2);

  __shared__ unsigned short As[2 * 128 * 64];  // 32 KB
  __shared__ unsigned short Bs[2 * 64 * 64];   // 16 KB

  const int t = threadIdx.x;
  const int lane = t & 63, w = t >> 6;
  const int wm = w >> 1, wn = w & 1;
  const int m0 = bx * 128, n0 = by * 64;
  const int lrow = lane & 15, lg = lane >> 4;

  f32x4 acc[4][2] = {};

  // per-wave staging chunk geometry (invariant)
  int arow[4], acol[4], brow[2], bcol[2];
#pragma unroll
  for (int p = 0; p < 4; ++p) {
    int c = (p * 4 + w) * 64 + lane;
    arow[p] = c >> 3; acol[p] = ((c & 7) ^ (arow[p] & 7)) * 8;
  }
#pragma unroll
  for (int p = 0; p < 2; ++p) {
    int c = (p * 4 + w) * 64 + lane;
    brow[p] = c >> 3; bcol[p] = ((c & 7) ^ (brow[p] & 7)) * 8;
  }

#define STAGE_G(kt, buf)                                                              \
  {                                                                                   \
    _Pragma("unroll") for (int p = 0; p < 4; ++p)                                     \
        gload16(&A[(size_t)(m0 + arow[p]) * K + (kt) + acol[p]],                      \
                &As[(buf)*8192 + ((p * 4 + w) * 64) * 8]);                            \
    _Pragma("unroll") for (int p = 0; p < 2; ++p)                                     \
        gload16(&W[(size_t)(n0 + brow[p]) * K + (kt) + bcol[p]],                      \
                &Bs[(buf)*4096 + ((p * 4 + w) * 64) * 8]);                            \
  }

#define COMPUTE(buf)                                                                  \
  {                                                                                   \
    _Pragma("unroll") for (int kc = 0; kc < 2; ++kc) {                                \
      short8 af[4], bfr[2];                                                           \
      _Pragma("unroll") for (int i = 0; i < 4; ++i)                                   \
          af[i] = lds8(As, (buf)*16384 + swz(wm * 64 + i * 16 + lrow, kc * 4 + lg));  \
      _Pragma("unroll") for (int i = 0; i < 2; ++i)                                   \
          bfr[i] = lds8(Bs, (buf)*8192 + swz(wn * 32 + i * 16 + lrow, kc * 4 + lg));  \
      _Pragma("unroll") for (int mi = 0; mi < 4; ++mi)                                \
          _Pragma("unroll") for (int ni = 0; ni < 2; ++ni)                            \
              acc[mi][ni] = MFMA16(af[mi], bfr[ni], acc[mi][ni]);                     \
    }                                                                                 \
  }

  // prologue: stage step 0, drain, rendezvous
  STAGE_G(0, 0);
  asm volatile("s_waitcnt vmcnt(0)" ::: "memory");
  __builtin_amdgcn_s_barrier();
  __builtin_amdgcn_sched_barrier(0);

  int cur = 0;
  for (int kt = 0; kt < K - 64; kt += 64) {
    STAGE_G(kt + 64, cur ^ 1);   // issue next step's loads first
    COMPUTE(cur);                // compute current step under the loads
    asm volatile("s_waitcnt vmcnt(0)" ::: "memory");
    __builtin_amdgcn_s_barrier();
    __builtin_amdgcn_sched_barrier(0);
    cur ^= 1;
  }
  COMPUTE(cur);  // peeled last step: no stage, no barrier
#undef STAGE_G
#undef COMPUTE

  const int r0 = lg * 4;
  if (MODE == 0) {
    const float scale = (z == 0) ? 0.18033688011112042f : 1.0f;  // fold log2(e)/8 into Q
    if (z < 2) {
      unsigned short* O = ObaseBf + (size_t)z * (size_t)M * N;
#pragma unroll
      for (int mi = 0; mi < 4; ++mi)
#pragma unroll
        for (int ni = 0; ni < 2; ++ni) {
          int e = n0 + wn * 32 + ni * 16 + lrow;
          float be = bias[e];
          int h = e >> 6, d = e & 63;
#pragma unroll
          for (int r = 0; r < 4; ++r) {
            int m = m0 + wm * 64 + mi * 16 + r0 + r;
            int s = m >> 1, bb = m & 1;
            O[(((size_t)(bb * 16 + h) * 2048 + s) << 6) + d] = f2bf((acc[mi][ni][r] + be) * scale);
          }
        }
    } else {
      // V^T: LDS-staged coalesced writes. Naive scatter = 64 lanes x 2B at 4KB
      // stride per store (64 L2 lines/inst); stage tile T[bb*64+d][72-pad][s_loc]
      // in LDS, then 128B-contiguous global stores.
      __builtin_amdgcn_s_barrier();  // all waves done reading As (peeled COMPUTE)
      unsigned short* T = As;        // reuse: need 128*72 = 9216 ushorts (<16384)
      const int h = n0 >> 6;
#pragma unroll
      for (int mi = 0; mi < 4; ++mi)
#pragma unroll
        for (int ni = 0; ni < 2; ++ni) {
          int d = wn * 32 + ni * 16 + lrow;
          float be = bias[n0 + d];
#pragma unroll
          for (int r = 0; r < 4; ++r) {
            int mrel = wm * 64 + mi * 16 + r0 + r;   // 0..127
            int sl = mrel >> 1, bb = mrel & 1;
            T[(bb * 64 + d) * 72 + sl] = f2bf(acc[mi][ni][r] + be);
          }
        }
      __builtin_amdgcn_s_barrier();
      unsigned short* O = ObaseBf + (size_t)2 * (size_t)M * N;  // Vt[bh][d][s]
#pragma unroll
      for (int pass = 0; pass < 4; ++pass) {
        int rr = pass * 32 + (t >> 3);     // 0..127 = bb*64 + d
        int sl8 = (t & 7) * 8;
        short8 vv = *reinterpret_cast<const short8*>(&T[rr * 72 + sl8]);
        int bb = rr >> 6, d = rr & 63;
        *reinterpret_cast<short8*>(
            &O[(((size_t)(bb * 16 + h) * 64 + d) << 11) + (m0 >> 1) + sl8]) = vv;
      }
    }
  } else {
    float* O = ObaseF;
#pragma unroll
    for (int mi = 0; mi < 4; ++mi)
#pragma unroll
      for (int ni = 0; ni < 2; ++ni) {
        int e = n0 + wn * 32 + ni * 16 + lrow;
        float be = bias[e];
#pragma unroll
        for (int r = 0; r < 4; ++r) {
          int m = m0 + wm * 64 + mi * 16 + r0 + r;
          O[(size_t)m * N + e] = acc[mi][ni][r] + be;
        }
      }
  }
}

// ---------------- Flash attention, 32x32 MFMA, swapped QK^T, 2-tile pipeline ----
// (round-8 version: ring-4, vmcnt(4), QK(t+1) overlaps exp/pack(t), grid 512)
__global__ __launch_bounds__(256, 2) void attn(const unsigned short* __restrict__ Q,
                                               const unsigned short* __restrict__ K,
                                               const unsigned short* __restrict__ Vt,
                                               unsigned short* __restrict__ ctx) {
  __shared__ unsigned short Ks[4 * 4096];  // ring of 4: [buf][64 key][64 dk]
  __shared__ unsigned short Vs[4 * 4096];  // ring of 4: [buf][64 d][64 key]

  // XCD swizzle: nwg=512, chunk=64 -> XCD x owns bh range [x*4, x*4+4)
  const int orig = blockIdx.x;
  const int wg = ((orig & 7) << 6) + (orig >> 3);
  const int bh = wg >> 4;
  const int qb = wg & 15;

  const int t = threadIdx.x, lane = t & 63, wv = t >> 6;
  const int q0 = qb * 128 + wv * 32;
  const int q = lane & 31, hi = lane >> 5;
  const int fq = (q ^ (q >> 3)) & 7;

  const unsigned short* Qb = Q + ((size_t)bh * 2048 + q0) * 64;
  const unsigned short* Kb = K + (size_t)bh * 2048 * 64;
  const unsigned short* Vb = Vt + (size_t)bh * 64 * 2048;

  short8 qf[4];
#pragma unroll
  for (int m = 0; m < 4; ++m)
    qf[m] = *reinterpret_cast<const short8*>(&Qb[q * 64 + m * 16 + hi * 8]);

  // loop-invariant LDS byte offsets (within one 8KB buffer)
  int koff[2][4], voff[2][2][2];
#pragma unroll
  for (int st = 0; st < 2; ++st) {
    int f = fq ^ (st ? 4 : 0);
#pragma unroll
    for (int m = 0; m < 4; ++m)
      koff[st][m] = (st * 32 + q) * 128 + (((m * 2 + hi) ^ f) << 4);
  }
#pragma unroll
  for (int dh = 0; dh < 2; ++dh) {
    int f = fq ^ (dh ? 4 : 0);
#pragma unroll
    for (int st = 0; st < 2; ++st)
#pragma unroll
      for (int kc = 0; kc < 2; ++kc)
        voff[dh][st][kc] = (dh * 32 + q) * 128 + (((st * 4 + kc * 2 + hi) ^ f) << 4);
  }

  // staging source addresses (pre-inverse-swizzled), advance per tile
  int c0 = wv * 64 + lane, c1 = (4 + wv) * 64 + lane;
  int sr0 = c0 >> 3, sr1 = c1 >> 3;
  int sc0c = ((c0 & 7) ^ ((sr0 ^ (sr0 >> 3)) & 7)) * 8;
  int sc1c = ((c1 & 7) ^ ((sr1 ^ (sr1 >> 3)) & 7)) * 8;
  const unsigned short* ks0 = Kb + (size_t)sr0 * 64 + sc0c;
  const unsigned short* ks1 = Kb + (size_t)sr1 * 64 + sc1c;
  const unsigned short* vp0 = Vb + (size_t)sr0 * 2048 + sc0c;
  const unsigned short* vp1 = Vb + (size_t)sr1 * 2048 + sc1c;

#define STAGE(tt)                                                      \
  {                                                                    \
    char* kb = (char*)Ks + ((tt) & 3) * 8192;                          \
    char* vb2 = (char*)Vs + ((tt) & 3) * 8192;                         \
    gload16(ks0, (unsigned short*)(kb + wv * 1024));                   \
    gload16(ks1, (unsigned short*)(kb + (4 + wv) * 1024));             \
    gload16(vp0, (unsigned short*)(vb2 + wv * 1024));                  \
    gload16(vp1, (unsigned short*)(vb2 + (4 + wv) * 1024));            \
    ks0 += 4096; ks1 += 4096; vp0 += 64; vp1 += 64;                    \
  }

  f32x16 oa0 = {}, oa1 = {};
  float lsum = 0.f;
  const f32x16 zero16 = {};
  f32x16 sA0 = {}, sA1 = {}, sB0, sB1;

  // prologue: stage tiles 0,1,2; rendezvous with tile0 resident; QK(0) -> sA
  STAGE(0); STAGE(1); STAGE(2);
  asm volatile("s_waitcnt vmcnt(8)" ::: "memory");
  __builtin_amdgcn_s_barrier();
  __builtin_amdgcn_sched_barrier(0);
#pragma unroll
  for (int m = 0; m < 4; ++m) {
    sA0 = MFMA32(lds8(Ks, koff[0][m]), qf[m], sA0);
    sA1 = MFMA32(lds8(Ks, koff[1][m]), qf[m], sA1);
  }

  // PHASE(tcur): wait tile tcur+1 resident; stage tcur+3; QK(tcur+1)->sN;
  //              exp/pack(sC) [overlaps QK on VALU pipe]; PV(tcur, pa).
#define PHASE(tcur, sC0, sC1, sN0, sN1)                                         \
  {                                                                             \
    asm volatile("s_waitcnt vmcnt(4)" ::: "memory");                            \
    __builtin_amdgcn_sched_barrier(0);                                          \
    __builtin_amdgcn_s_barrier();                                               \
    __builtin_amdgcn_sched_barrier(0);                                          \
    STAGE((tcur) + 3);                                                          \
    sN0 = zero16; sN1 = zero16;                                                 \
    __builtin_amdgcn_s_setprio(1);                                              \
    {                                                                           \
      const int so = (((tcur) + 1) & 3) * 8192;                                 \
      _Pragma("unroll") for (int m = 0; m < 4; ++m) {                           \
        sN0 = MFMA32(lds8(Ks, so + koff[0][m]), qf[m], sN0);                    \
        sN1 = MFMA32(lds8(Ks, so + koff[1][m]), qf[m], sN1);                    \
      }                                                                         \
    }                                                                           \
    short8 paL0, paH0, paL1, paH1;                                              \
    exppack(sC0, lsum, paL0, paH0);                                             \
    exppack(sC1, lsum, paL1, paH1);                                             \
    {                                                                           \
      const int vo = ((tcur) & 3) * 8192;                                       \
      oa0 = MFMA32(paL0, lds8(Vs, vo + voff[0][0][0]), oa0);                    \
      oa1 = MFMA32(paL0, lds8(Vs, vo + voff[1][0][0]), oa1);                    \
      oa0 = MFMA32(paH0, lds8(Vs, vo + voff[0][0][1]), oa0);                    \
      oa1 = MFMA32(paH0, lds8(Vs, vo + voff[1][0][1]), oa1);                    \
      oa0 = MFMA32(paL1, lds8(Vs, vo + voff[0][1][0]), oa0);                    \
      oa1 = MFMA32(paL1, lds8(Vs, vo + voff[1][1][0]), oa1);                    \
      oa0 = MFMA32(paH1, lds8(Vs, vo + voff[0][1][1]), oa0);                    \
      oa1 = MFMA32(paH1, lds8(Vs, vo + voff[1][1][1]), oa1);                    \
    }                                                                           \
    __builtin_amdgcn_s_setprio(0);                                              \
  }

  for (int it = 0; it < 15; ++it) {
    int tc = 2 * it;
    PHASE(tc, sA0, sA1, sB0, sB1);
    PHASE(tc + 1, sB0, sB1, sA0, sA1);
  }
  PHASE(30, sA0, sA1, sB0, sB1);  // QK(31)->sB, PV(30)

  // tail: tile 31 (slot 3) from sB; V(31) resident since PHASE(30)'s wait+barrier
  {
    short8 paL0, paH0, paL1, paH1;
    exppack(sB0, lsum, paL0, paH0);
    exppack(sB1, lsum, paL1, paH1);
    const int vo = 3 * 8192;
    oa0 = MFMA32(paL0, lds8(Vs, vo + voff[0][0][0]), oa0);
    oa1 = MFMA32(paL0, lds8(Vs, vo + voff[1][0][0]), oa1);
    oa0 = MFMA32(paH0, lds8(Vs, vo + voff[0][0][1]), oa0);
    oa1 = MFMA32(paH0, lds8(Vs, vo + voff[1][0][1]), oa1);
    oa0 = MFMA32(paL1, lds8(Vs, vo + voff[0][1][0]), oa0);
    oa1 = MFMA32(paL1, lds8(Vs, vo + voff[1][1][0]), oa1);
    oa0 = MFMA32(paH1, lds8(Vs, vo + voff[0][1][1]), oa0);
    oa1 = MFMA32(paH1, lds8(Vs, vo + voff[1][1][1]), oa1);
  }
#undef PHASE
#undef STAGE

  // epilogue: combine hi/lo key-half sums, normalize, store
  lsum = swapadd(lsum);
  float linv = 1.0f / lsum;
  const int b = bh >> 4, h = bh & 15;
#pragma unroll
  for (int r = 0; r < 16; ++r) {
    int qr = (r & 3) + 8 * (r >> 2) + 4 * hi;
    float li = __shfl(linv, qr);
    size_t base = ((size_t)(q0 + qr) * 2 + b) * 1024 + h * 64 + q;
    ctx[base] = f2bf(oa0[r] * li);
    ctx[base + 32] = f2bf(oa1[r] * li);
  }
}

// ---------------- host ----------------
extern "C" void kernel_launch(void* const* d_in, const int* in_sizes, int n_in, void* d_out,
                              int out_size, void* d_ws, size_t ws_size, hipStream_t stream) {
  const float* q  = (const float*)d_in[0];
  const float* k  = (const float*)d_in[1];
  const float* v  = (const float*)d_in[2];
  const float* Wq = (const float*)d_in[3];
  const float* bq = (const float*)d_in[4];
  const float* Wk = (const float*)d_in[5];
  const float* bk = (const float*)d_in[6];
  const float* Wv = (const float*)d_in[7];
  const float* bv = (const float*)d_in[8];
  const float* Wo = (const float*)d_in[9];
  const float* bo = (const float*)d_in[10];

  const size_t SZ_IN = 4194304;  // 4096*1024
  const size_t SZ_W  = 1048576;  // 1024*1024
  unsigned short* ws  = (unsigned short*)d_ws;
  unsigned short* xb  = ws;                 // q,k,v bf16       (3*SZ_IN)
  unsigned short* Wb  = xb + 3 * SZ_IN;     // Wq,Wk,Wv,Wo bf16 (4*SZ_W)
  unsigned short* QKV = Wb + 4 * SZ_W;      // Q,K (by-head), Vt (transposed)
  unsigned short* ctx = QKV + 3 * SZ_IN;    // context          (SZ_IN)

  cvt_bf16x<<<dim3(SZ_IN / 2048, 3), 256, 0, stream>>>(q, k, v, v, xb, (int)SZ_IN);
  cvt_bf16x<<<dim3(SZ_W / 2048, 4), 256, 0, stream>>>(Wq, Wk, Wv, Wo, Wb, (int)SZ_W);

  gemm_bt<0><<<1536, 256, 0, stream>>>(xb, Wb, bq, bk, bv, QKV, nullptr, 4096, 1024, 1024);
  attn<<<512, 256, 0, stream>>>(QKV, QKV + SZ_IN, QKV + 2 * SZ_IN, ctx);
  gemm_bt<1><<<512, 256, 0, stream>>>(ctx, Wb + 3 * SZ_W, bo, bo, bo, nullptr,
                                      (float*)d_out, 4096, 1024, 1024);
}